// Round 1
// baseline (524.437 us; speedup 1.0000x reference)
//
#include <hip/hip_runtime.h>
#include <hip/hip_bf16.h>

typedef __attribute__((ext_vector_type(8))) short s16x8;
typedef __attribute__((ext_vector_type(4))) short s16x4;
typedef __attribute__((ext_vector_type(4))) float f32x4;

#define MOD_SCALE 0.014731391274719739f  // 1/sqrt(512*9)
#define CIPAD 36

// ---------------------------------------------------------------------------
// Kernel 1: x[b][ci][h][w] fp32 -> xb[b][h][w][ci] bf16, folding SCALE*style
// LDS-tiled transpose: coalesced reads along w, coalesced writes along ci.
// grid (4 ci-chunks, 64 h, 8 b), 256 threads
// ---------------------------------------------------------------------------
__global__ __launch_bounds__(256) void k_xprep(const float* __restrict__ x,
                                               const float* __restrict__ style,
                                               __hip_bfloat16* __restrict__ xb) {
    const int cig = blockIdx.x, h = blockIdx.y, b = blockIdx.z;
    const int ci0 = cig * 128;
    __shared__ __align__(16) __hip_bfloat16 tile[64][130];  // [w][c], pad
    const int t = threadIdx.x;
    const int wl = t & 63, cl4 = t >> 6;
    for (int r = 0; r < 32; ++r) {
        int c = r * 4 + cl4;
        float v = x[(((size_t)b * 512 + ci0 + c) * 64 + h) * 64 + wl];
        float s = style[b * 512 + ci0 + c];
        tile[wl][c] = __float2bfloat16(v * s * MOD_SCALE);
    }
    __syncthreads();
    const int w4 = t >> 6;           // 0..3
    const int cp = (t & 63) * 2;     // 0..126 even
    for (int r = 0; r < 16; ++r) {
        int w = r * 4 + w4;
        unsigned v = *(const unsigned*)(&tile[w][cp]);
        *(unsigned*)(&xb[(((size_t)b * 64 + h) * 64 + w) * 512 + ci0 + cp]) = v;
    }
}

// ---------------------------------------------------------------------------
// Kernel 2: weight[co][ci][kh][kw] fp32 -> wb[tap][co][ci] bf16
// 1024 blocks x 256 threads, one thread per (co,ci)
// ---------------------------------------------------------------------------
__global__ __launch_bounds__(256) void k_wprep(const float* __restrict__ w,
                                               __hip_bfloat16* __restrict__ wb) {
    const int idx = blockIdx.x * 256 + threadIdx.x;  // 0..262143 = co*512+ci
    const float* src = w + (size_t)idx * 9;
#pragma unroll
    for (int tap = 0; tap < 9; ++tap)
        wb[(size_t)tap * 262144 + idx] = __float2bfloat16(src[tap]);
}

// ---------------------------------------------------------------------------
// Kernel 3: demod[b][co] = rsqrt(SCALE^2 * sum_ci style^2 * sum_kk w^2 + 1e-8)
// 512 blocks (one per co) x 256 threads, fp32 throughout
// ---------------------------------------------------------------------------
__global__ __launch_bounds__(256) void k_demod(const float* __restrict__ w,
                                               const float* __restrict__ style,
                                               float* __restrict__ dem) {
    const int co = blockIdx.x;
    const int t = threadIdx.x;
    float accb[8] = {0.f, 0.f, 0.f, 0.f, 0.f, 0.f, 0.f, 0.f};
    for (int ci = t; ci < 512; ci += 256) {
        const float* wp = w + ((size_t)co * 512 + ci) * 9;
        float ws = 0.f;
#pragma unroll
        for (int k = 0; k < 9; ++k) { float v = wp[k]; ws += v * v; }
#pragma unroll
        for (int bb = 0; bb < 8; ++bb) {
            float s = style[bb * 512 + ci];
            accb[bb] += s * s * ws;
        }
    }
    __shared__ float red[256];
    const float S2 = MOD_SCALE * MOD_SCALE;
    for (int bb = 0; bb < 8; ++bb) {
        red[t] = accb[bb];
        __syncthreads();
        for (int off = 128; off > 0; off >>= 1) {
            if (t < off) red[t] += red[t + off];
            __syncthreads();
        }
        if (t == 0) dem[bb * 512 + co] = rsqrtf(S2 * red[0] + 1e-8f);
        __syncthreads();
    }
}

// ---------------------------------------------------------------------------
// Kernel 4: implicit-GEMM conv. Block tile: 128 co x 128 spatial (2 rows).
// K-loop: 9 taps x 16 ci-blocks of 32. 4 waves (2x2), each 4x4 frags of
// mfma_f32_16x16x32_bf16 (A=W: m=co, B=X: n=w). 1024 blocks x 256 threads.
// ---------------------------------------------------------------------------
__global__ __launch_bounds__(256) void k_conv(const __hip_bfloat16* __restrict__ xb,
                                              const __hip_bfloat16* __restrict__ wb,
                                              const float* __restrict__ demod,
                                              const float* __restrict__ noise,
                                              const float* __restrict__ bias,
                                              const float* __restrict__ nstr,
                                              float* __restrict__ out) {
    __shared__ __align__(16) __hip_bfloat16 Wl[128 * CIPAD];      // [co][ci pad 36]
    __shared__ __align__(16) __hip_bfloat16 Xl[2 * 66 * CIPAD];   // [row][col][ci pad 36]

    const int t = threadIdx.x;
    const int bi = blockIdx.x;
    const int co0 = (bi & 3) * 128;
    const int h0 = ((bi >> 2) & 31) * 2;
    const int b = bi >> 7;
    const int lane = t & 63;
    const int wv = t >> 6;
    const int wm = wv & 1, wn = wv >> 1;
    const int q = lane >> 4, ln = lane & 15;

    f32x4 acc[4][4];
#pragma unroll
    for (int i = 0; i < 4; ++i)
#pragma unroll
        for (int j = 0; j < 4; ++j) acc[i][j] = (f32x4){0.f, 0.f, 0.f, 0.f};

    // W staging: 512 groups of 8 bf16 (128 co x 4 groups); thread t does
    // groups (co=t>>2, t>>2+64) at element offset (t&3)*8.
    const int wco = t >> 2;
    const int wcig = (t & 3) * 8;
    // X staging: threads 0..131 -> (row 0/1, col 0..65), 32 ci each (64B)
    const int xr = (t >= 66) ? 1 : 0;
    const int xc = t - 66 * xr;
    const bool xact = t < 132;

    const __hip_bfloat16* xbb = xb + (size_t)b * 64 * 64 * 512;

    for (int tap = 0; tap < 9; ++tap) {
        const int dh = tap / 3, dw = tap % 3;
        const int r_img = h0 + dh - 1 + xr;
        const int wc = xc - 1;
        const bool xvalid = xact && ((unsigned)r_img < 64u) && ((unsigned)wc < 64u);
        const __hip_bfloat16* xsrc0 = xbb + ((size_t)(r_img * 64 + wc)) * 512;
        const __hip_bfloat16* wsrc0 =
            wb + (size_t)tap * 262144 + (size_t)(co0 + wco) * 512 + wcig;
        __hip_bfloat16* xdst = Xl + (xr * 66 + xc) * CIPAD;

        for (int cb = 0; cb < 16; ++cb) {
            const int ci0 = cb * 32;
            // ---- stage W tile (128 x 32) ----
            {
                float4 v0 = *(const float4*)(wsrc0 + ci0);
                float4 v1 = *(const float4*)(wsrc0 + 64 * 512 + ci0);
                float2* d0 = (float2*)(Wl + wco * CIPAD + wcig);
                float2* d1 = (float2*)(Wl + (wco + 64) * CIPAD + wcig);
                d0[0] = make_float2(v0.x, v0.y); d0[1] = make_float2(v0.z, v0.w);
                d1[0] = make_float2(v1.x, v1.y); d1[1] = make_float2(v1.z, v1.w);
            }
            // ---- stage X halo tile (2 x 66 x 32) ----
            if (xact) {
                if (xvalid) {
                    const float4* s = (const float4*)(xsrc0 + ci0);
#pragma unroll
                    for (int k = 0; k < 4; ++k) {
                        float4 v = s[k];
                        float2* d = (float2*)(xdst + k * 8);
                        d[0] = make_float2(v.x, v.y); d[1] = make_float2(v.z, v.w);
                    }
                } else {
                    float2 z = make_float2(0.f, 0.f);
#pragma unroll
                    for (int k = 0; k < 4; ++k) {
                        float2* d = (float2*)(xdst + k * 8);
                        d[0] = z; d[1] = z;
                    }
                }
            }
            __syncthreads();
            // ---- fragments ----
            s16x8 af[4], bfr[4];
#pragma unroll
            for (int mi = 0; mi < 4; ++mi) {
                const s16x4* p =
                    (const s16x4*)(Wl + (wm * 64 + mi * 16 + ln) * CIPAD + q * 8);
                s16x4 a0 = p[0], a1 = p[1];
                af[mi] = (s16x8){a0[0], a0[1], a0[2], a0[3], a1[0], a1[1], a1[2], a1[3]};
            }
#pragma unroll
            for (int ni = 0; ni < 4; ++ni) {
                const s16x4* p =
                    (const s16x4*)(Xl + (wn * 66 + ni * 16 + ln + dw) * CIPAD + q * 8);
                s16x4 b0 = p[0], b1 = p[1];
                bfr[ni] = (s16x8){b0[0], b0[1], b0[2], b0[3], b1[0], b1[1], b1[2], b1[3]};
            }
#pragma unroll
            for (int mi = 0; mi < 4; ++mi)
#pragma unroll
                for (int ni = 0; ni < 4; ++ni)
                    acc[mi][ni] = __builtin_amdgcn_mfma_f32_16x16x32_bf16(
                        af[mi], bfr[ni], acc[mi][ni], 0, 0, 0);
            __syncthreads();
        }
    }

    // ---- epilogue: *demod + noise*strength + bias, leaky_relu(0.2)*sqrt(2) ----
    const float nsv = nstr[0];
    const int h = h0 + wn;
    const float LR = 1.4142135623730951f;
#pragma unroll
    for (int mi = 0; mi < 4; ++mi) {
        float dm[4], bs[4];
#pragma unroll
        for (int r = 0; r < 4; ++r) {
            int co = co0 + wm * 64 + mi * 16 + q * 4 + r;
            dm[r] = demod[b * 512 + co];
            bs[r] = bias[co];
        }
#pragma unroll
        for (int ni = 0; ni < 4; ++ni) {
            int w = ni * 16 + ln;
            float nz = nsv * noise[h * 64 + w];
#pragma unroll
            for (int r = 0; r < 4; ++r) {
                int co = co0 + wm * 64 + mi * 16 + q * 4 + r;
                float v = acc[mi][ni][r] * dm[r] + nz + bs[r];
                v = (v >= 0.f ? v : 0.2f * v) * LR;
                out[(((size_t)b * 512 + co) * 64 + h) * 64 + w] = v;
            }
        }
    }
}

// ---------------------------------------------------------------------------
extern "C" void kernel_launch(void* const* d_in, const int* in_sizes, int n_in,
                              void* d_out, int out_size, void* d_ws, size_t ws_size,
                              hipStream_t stream) {
    const float* x      = (const float*)d_in[0];
    const float* style  = (const float*)d_in[1];
    const float* noise  = (const float*)d_in[2];
    const float* weight = (const float*)d_in[3];
    const float* bias   = (const float*)d_in[4];
    const float* nstr   = (const float*)d_in[5];
    float* out = (float*)d_out;

    char* ws = (char*)d_ws;
    __hip_bfloat16* xb = (__hip_bfloat16*)ws;                       // 33,554,432 B
    __hip_bfloat16* wb = (__hip_bfloat16*)(ws + 33554432);          //  4,718,592 B
    float* demod = (float*)(ws + 33554432 + 4718592);               //     16,384 B

    k_xprep<<<dim3(4, 64, 8), 256, 0, stream>>>(x, style, xb);
    k_wprep<<<1024, 256, 0, stream>>>(weight, wb);
    k_demod<<<512, 256, 0, stream>>>(weight, style, demod);
    k_conv<<<1024, 256, 0, stream>>>(xb, wb, demod, noise, bias, nstr, out);
}

// Round 2
// 310.262 us; speedup vs baseline: 1.6903x; 1.6903x over previous
//
#include <hip/hip_runtime.h>
#include <hip/hip_bf16.h>

typedef __attribute__((ext_vector_type(8))) short s16x8;
typedef __attribute__((ext_vector_type(4))) float f32x4;

#define MOD_SCALE 0.014731391274719739f  // 1/sqrt(512*9)
#define CIPAD 40                          // 80B rows: 16B-aligned, 20-bank stride

// ---------------------------------------------------------------------------
// Kernel 0: zero the 1-px border of padded image xs[8][66][66][512] (bf16).
// 520 blocks x 256 threads, one uint4 (8 bf16) per thread.
// ---------------------------------------------------------------------------
__global__ __launch_bounds__(256) void k_border(__hip_bfloat16* __restrict__ xs) {
    const int idx = blockIdx.x * 256 + threadIdx.x;   // 0..133119
    const int b = idx / 16640;
    const int r2 = idx - b * 16640;
    const int pair = r2 >> 6;        // 0..259
    const int ciq = r2 & 63;         // uint4 index within 512 ci
    int pr, pc;
    if (pair < 66)       { pr = 0;          pc = pair; }
    else if (pair < 132) { pr = 65;         pc = pair - 66; }
    else if (pair < 196) { pr = pair - 131; pc = 0; }
    else                 { pr = pair - 195; pc = 65; }
    uint4* d = (uint4*)(xs + (((size_t)b * 66 + pr) * 66 + pc) * 512) + ciq;
    *d = make_uint4(0u, 0u, 0u, 0u);
}

// ---------------------------------------------------------------------------
// Kernel 1: x[b][ci][h][w] fp32 -> xs[b][h+1][w+1][ci] bf16 (padded,
// channels-last), folding SCALE*style. LDS-tiled transpose.
// grid (4 ci-chunks, 64 h, 8 b), 256 threads
// ---------------------------------------------------------------------------
__global__ __launch_bounds__(256) void k_xprep(const float* __restrict__ x,
                                               const float* __restrict__ style,
                                               __hip_bfloat16* __restrict__ xs) {
    const int cig = blockIdx.x, h = blockIdx.y, b = blockIdx.z;
    const int ci0 = cig * 128;
    __shared__ __align__(16) __hip_bfloat16 tile[64][130];  // [w][c], pad
    const int t = threadIdx.x;
    const int wl = t & 63, cl4 = t >> 6;
    for (int r = 0; r < 32; ++r) {
        int c = r * 4 + cl4;
        float v = x[(((size_t)b * 512 + ci0 + c) * 64 + h) * 64 + wl];
        float s = style[b * 512 + ci0 + c];
        tile[wl][c] = __float2bfloat16(v * s * MOD_SCALE);
    }
    __syncthreads();
    const int w4 = t >> 6;           // 0..3
    const int cp = (t & 63) * 2;     // 0..126 even
    for (int r = 0; r < 16; ++r) {
        int w = r * 4 + w4;
        unsigned v = *(const unsigned*)(&tile[w][cp]);
        *(unsigned*)(&xs[(((size_t)b * 66 + h + 1) * 66 + (w + 1)) * 512 +
                         ci0 + cp]) = v;
    }
}

// ---------------------------------------------------------------------------
// Kernel 2: weight[co][ci][kh][kw] fp32 -> wb[tap][co][ci] bf16
// ---------------------------------------------------------------------------
__global__ __launch_bounds__(256) void k_wprep(const float* __restrict__ w,
                                               __hip_bfloat16* __restrict__ wb) {
    const int idx = blockIdx.x * 256 + threadIdx.x;  // co*512+ci
    const float* src = w + (size_t)idx * 9;
#pragma unroll
    for (int tap = 0; tap < 9; ++tap)
        wb[(size_t)tap * 262144 + idx] = __float2bfloat16(src[tap]);
}

// ---------------------------------------------------------------------------
// Kernel 3: demod[b][co] = rsqrt(SCALE^2 * sum_ci style^2 * sum_kk w^2 + 1e-8)
// ---------------------------------------------------------------------------
__global__ __launch_bounds__(256) void k_demod(const float* __restrict__ w,
                                               const float* __restrict__ style,
                                               float* __restrict__ dem) {
    const int co = blockIdx.x;
    const int t = threadIdx.x;
    float accb[8] = {0.f, 0.f, 0.f, 0.f, 0.f, 0.f, 0.f, 0.f};
    for (int ci = t; ci < 512; ci += 256) {
        const float* wp = w + ((size_t)co * 512 + ci) * 9;
        float ws = 0.f;
#pragma unroll
        for (int k = 0; k < 9; ++k) { float v = wp[k]; ws += v * v; }
#pragma unroll
        for (int bb = 0; bb < 8; ++bb) {
            float s = style[bb * 512 + ci];
            accb[bb] += s * s * ws;
        }
    }
    __shared__ float red[256];
    const float S2 = MOD_SCALE * MOD_SCALE;
    for (int bb = 0; bb < 8; ++bb) {
        red[t] = accb[bb];
        __syncthreads();
        for (int off = 128; off > 0; off >>= 1) {
            if (t < off) red[t] += red[t + off];
            __syncthreads();
        }
        if (t == 0) dem[bb * 512 + co] = rsqrtf(S2 * red[0] + 1e-8f);
        __syncthreads();
    }
}

// ---------------------------------------------------------------------------
// Kernel 4: implicit-GEMM conv, restructured K-loop.
// Block: 128 co x 128 spatial (2 rows x 64 w). 4 waves 2x2.
// Outer loop: 16 ci-blocks of 32. Per ci-block: stage X once (4 padded rows
// x 66 cols -> serves all 9 taps via LDS offsets), stage W in 3-tap groups.
// Barriers: 96/block (was 288); all frag reads ds_read_b128.
// ---------------------------------------------------------------------------
__global__ __launch_bounds__(256, 2) void k_conv(
    const __hip_bfloat16* __restrict__ xs,   // [8][66][66][512] padded
    const __hip_bfloat16* __restrict__ wb,   // [9][512][512] tap-major
    const float* __restrict__ demod,
    const float* __restrict__ noise,
    const float* __restrict__ bias,
    const float* __restrict__ nstr,
    float* __restrict__ out) {
    __shared__ __align__(16) __hip_bfloat16 Xl[4 * 66 * CIPAD];   // 21120 B
    __shared__ __align__(16) __hip_bfloat16 Wl[3 * 128 * CIPAD];  // 30720 B

    const int t = threadIdx.x;
    const int bi = blockIdx.x;
    const int co0 = (bi & 3) * 128;
    const int h0 = ((bi >> 2) & 31) * 2;
    const int b = bi >> 7;
    const int lane = t & 63;
    const int wv = t >> 6;
    const int wm = wv & 1, wn = wv >> 1;
    const int q = lane >> 4, ln = lane & 15;

    f32x4 acc[4][4];
#pragma unroll
    for (int i = 0; i < 4; ++i)
#pragma unroll
        for (int j = 0; j < 4; ++j) acc[i][j] = (f32x4){0.f, 0.f, 0.f, 0.f};

    // X staging: pair p -> (row p/66, col p%66), 32 ci = 64 B each.
    const int xp_r = t / 66, xp_c = t - xp_r * 66;
    // W staging: thread -> (co t>>1, 16-ci half t&1), for 3 taps.
    const int wco = t >> 1, wpart = t & 1;

    const __hip_bfloat16* xsb = xs + (size_t)b * 66 * 66 * 512;

    for (int cb = 0; cb < 16; ++cb) {
        const int ci0 = cb * 32;
        __syncthreads();  // prior iteration's frag reads done
        // ---- stage X: 4 rows x 66 cols x 32 ci ----
        {
            const float4* s =
                (const float4*)(xsb + (((h0 + xp_r) * 66 + xp_c) << 9) + ci0);
            float4 v0 = s[0], v1 = s[1], v2 = s[2], v3 = s[3];
            float4* d = (float4*)(Xl + (xp_r * 66 + xp_c) * CIPAD);
            d[0] = v0; d[1] = v1; d[2] = v2; d[3] = v3;
            if (t < 8) {  // pairs 256..263 (row 3, cols 58..65)
                const float4* s2 =
                    (const float4*)(xsb + (((h0 + 3) * 66 + 58 + t) << 9) + ci0);
                float4 u0 = s2[0], u1 = s2[1], u2 = s2[2], u3 = s2[3];
                float4* d2 = (float4*)(Xl + (3 * 66 + 58 + t) * CIPAD);
                d2[0] = u0; d2[1] = u1; d2[2] = u2; d2[3] = u3;
            }
        }
        // ---- stage W taps 0..2 (dh=0) ----
#pragma unroll
        for (int rr = 0; rr < 3; ++rr) {
            const float4* s = (const float4*)(wb + (size_t)rr * 262144 +
                                              ((co0 + wco) << 9) + ci0 + wpart * 16);
            float4 v0 = s[0], v1 = s[1];
            float4* d = (float4*)(Wl + (rr * 128 + wco) * CIPAD + wpart * 16);
            d[0] = v0; d[1] = v1;
        }
        __syncthreads();

        for (int dh = 0; dh < 3; ++dh) {
            if (dh) {
                __syncthreads();  // waves done reading Wl for dh-1
#pragma unroll
                for (int rr = 0; rr < 3; ++rr) {
                    const float4* s =
                        (const float4*)(wb + (size_t)(dh * 3 + rr) * 262144 +
                                        ((co0 + wco) << 9) + ci0 + wpart * 16);
                    float4 v0 = s[0], v1 = s[1];
                    float4* d =
                        (float4*)(Wl + (rr * 128 + wco) * CIPAD + wpart * 16);
                    d[0] = v0; d[1] = v1;
                }
                __syncthreads();
            }
            const int xrow = dh + wn;  // local row in Xl
#pragma unroll
            for (int dw = 0; dw < 3; ++dw) {
                s16x8 af[4], bfr[4];
#pragma unroll
                for (int mi = 0; mi < 4; ++mi)
                    af[mi] = *(const s16x8*)(Wl +
                        (dw * 128 + wm * 64 + mi * 16 + ln) * CIPAD + q * 8);
#pragma unroll
                for (int ni = 0; ni < 4; ++ni)
                    bfr[ni] = *(const s16x8*)(Xl +
                        (xrow * 66 + ni * 16 + ln + dw) * CIPAD + q * 8);
#pragma unroll
                for (int mi = 0; mi < 4; ++mi)
#pragma unroll
                    for (int ni = 0; ni < 4; ++ni)
                        acc[mi][ni] = __builtin_amdgcn_mfma_f32_16x16x32_bf16(
                            af[mi], bfr[ni], acc[mi][ni], 0, 0, 0);
            }
        }
    }

    // ---- epilogue: *demod + noise*strength + bias, leaky_relu(0.2)*sqrt(2) ----
    const float nsv = nstr[0];
    const int h = h0 + wn;
    const float LR = 1.4142135623730951f;
#pragma unroll
    for (int mi = 0; mi < 4; ++mi) {
        float dm[4], bs[4];
#pragma unroll
        for (int r = 0; r < 4; ++r) {
            int co = co0 + wm * 64 + mi * 16 + q * 4 + r;
            dm[r] = demod[b * 512 + co];
            bs[r] = bias[co];
        }
#pragma unroll
        for (int ni = 0; ni < 4; ++ni) {
            int w = ni * 16 + ln;
            float nz = nsv * noise[h * 64 + w];
#pragma unroll
            for (int r = 0; r < 4; ++r) {
                int co = co0 + wm * 64 + mi * 16 + q * 4 + r;
                float v = acc[mi][ni][r] * dm[r] + nz + bs[r];
                v = (v >= 0.f ? v : 0.2f * v) * LR;
                out[(((size_t)b * 512 + co) * 64 + h) * 64 + w] = v;
            }
        }
    }
}

// ---------------------------------------------------------------------------
extern "C" void kernel_launch(void* const* d_in, const int* in_sizes, int n_in,
                              void* d_out, int out_size, void* d_ws, size_t ws_size,
                              hipStream_t stream) {
    const float* x      = (const float*)d_in[0];
    const float* style  = (const float*)d_in[1];
    const float* noise  = (const float*)d_in[2];
    const float* weight = (const float*)d_in[3];
    const float* bias   = (const float*)d_in[4];
    const float* nstr   = (const float*)d_in[5];
    float* out = (float*)d_out;

    char* ws = (char*)d_ws;
    __hip_bfloat16* xs = (__hip_bfloat16*)ws;              // 35,684,352 B padded
    __hip_bfloat16* wb = (__hip_bfloat16*)(ws + 35684352); //  4,718,592 B
    float* demod = (float*)(ws + 35684352 + 4718592);      //     16,384 B

    k_border<<<520, 256, 0, stream>>>(xs);
    k_xprep<<<dim3(4, 64, 8), 256, 0, stream>>>(x, style, xs);
    k_wprep<<<1024, 256, 0, stream>>>(weight, wb);
    k_demod<<<512, 256, 0, stream>>>(weight, style, demod);
    k_conv<<<1024, 256, 0, stream>>>(xs, wb, demod, noise, bias, nstr, out);
}

// Round 3
// 288.951 us; speedup vs baseline: 1.8150x; 1.0738x over previous
//
#include <hip/hip_runtime.h>
#include <hip/hip_bf16.h>

typedef __attribute__((ext_vector_type(8))) short s16x8;
typedef __attribute__((ext_vector_type(4))) float f32x4;

#define MOD_SCALE 0.014731391274719739f  // 1/sqrt(512*9)

__device__ __forceinline__ void gload_lds16(const void* g, void* l) {
    __builtin_amdgcn_global_load_lds(
        (const __attribute__((address_space(1))) unsigned int*)g,
        (__attribute__((address_space(3))) unsigned int*)l, 16, 0, 0);
}

// ---------------------------------------------------------------------------
// Kernel 0: zero the 1-px border of padded image xs[8][66][66][512] (bf16).
// ---------------------------------------------------------------------------
__global__ __launch_bounds__(256) void k_border(__hip_bfloat16* __restrict__ xs) {
    const int idx = blockIdx.x * 256 + threadIdx.x;   // 0..133119
    const int b = idx / 16640;
    const int r2 = idx - b * 16640;
    const int pair = r2 >> 6;        // 0..259
    const int ciq = r2 & 63;         // uint4 index within 512 ci
    int pr, pc;
    if (pair < 66)       { pr = 0;          pc = pair; }
    else if (pair < 132) { pr = 65;         pc = pair - 66; }
    else if (pair < 196) { pr = pair - 131; pc = 0; }
    else                 { pr = pair - 195; pc = 65; }
    uint4* d = (uint4*)(xs + (((size_t)b * 66 + pr) * 66 + pc) * 512) + ciq;
    *d = make_uint4(0u, 0u, 0u, 0u);
}

// ---------------------------------------------------------------------------
// Kernel 1: x[b][ci][h][w] fp32 -> xs[b][h+1][w+1][ci] bf16 (padded,
// channels-last), folding SCALE*style. LDS-tiled transpose.
// ---------------------------------------------------------------------------
__global__ __launch_bounds__(256) void k_xprep(const float* __restrict__ x,
                                               const float* __restrict__ style,
                                               __hip_bfloat16* __restrict__ xs) {
    const int cig = blockIdx.x, h = blockIdx.y, b = blockIdx.z;
    const int ci0 = cig * 128;
    __shared__ __align__(16) __hip_bfloat16 tile[64][130];  // [w][c], pad
    const int t = threadIdx.x;
    const int wl = t & 63, cl4 = t >> 6;
    for (int r = 0; r < 32; ++r) {
        int c = r * 4 + cl4;
        float v = x[(((size_t)b * 512 + ci0 + c) * 64 + h) * 64 + wl];
        float s = style[b * 512 + ci0 + c];
        tile[wl][c] = __float2bfloat16(v * s * MOD_SCALE);
    }
    __syncthreads();
    const int w4 = t >> 6;           // 0..3
    const int cp = (t & 63) * 2;     // 0..126 even
    for (int r = 0; r < 16; ++r) {
        int w = r * 4 + w4;
        unsigned v = *(const unsigned*)(&tile[w][cp]);
        *(unsigned*)(&xs[(((size_t)b * 66 + h + 1) * 66 + (w + 1)) * 512 +
                         ci0 + cp]) = v;
    }
}

// ---------------------------------------------------------------------------
// Kernel 2: weight[co][ci][kh][kw] fp32 -> wb[tap][co][ci] bf16.
// LDS round-trip so both global read and write are coalesced.
// Block handles 256 (co,ci) pairs = 2304 consecutive floats.
// ---------------------------------------------------------------------------
__global__ __launch_bounds__(256) void k_wprep(const float* __restrict__ w,
                                               __hip_bfloat16* __restrict__ wb) {
    __shared__ float lds[2304];
    const int t = threadIdx.x;
    const int p0 = blockIdx.x * 256;          // first pair (co*512+ci)
    const float* src = w + (size_t)p0 * 9;
#pragma unroll
    for (int k = 0; k < 9; ++k) lds[k * 256 + t] = src[k * 256 + t];
    __syncthreads();
#pragma unroll
    for (int tap = 0; tap < 9; ++tap)
        wb[(size_t)tap * 262144 + p0 + t] = __float2bfloat16(lds[t * 9 + tap]);
}

// ---------------------------------------------------------------------------
// Kernel 3: demod[b][co] = rsqrt(SCALE^2 * sum_ci style^2 * sum_kk w^2 + 1e-8)
// ---------------------------------------------------------------------------
__global__ __launch_bounds__(256) void k_demod(const float* __restrict__ w,
                                               const float* __restrict__ style,
                                               float* __restrict__ dem) {
    const int co = blockIdx.x;
    const int t = threadIdx.x;
    float accb[8] = {0.f, 0.f, 0.f, 0.f, 0.f, 0.f, 0.f, 0.f};
    for (int ci = t; ci < 512; ci += 256) {
        const float* wp = w + ((size_t)co * 512 + ci) * 9;
        float ws = 0.f;
#pragma unroll
        for (int k = 0; k < 9; ++k) { float v = wp[k]; ws += v * v; }
#pragma unroll
        for (int bb = 0; bb < 8; ++bb) {
            float s = style[bb * 512 + ci];
            accb[bb] += s * s * ws;
        }
    }
    __shared__ float red[256];
    const float S2 = MOD_SCALE * MOD_SCALE;
    for (int bb = 0; bb < 8; ++bb) {
        red[t] = accb[bb];
        __syncthreads();
        for (int off = 128; off > 0; off >>= 1) {
            if (t < off) red[t] += red[t + off];
            __syncthreads();
        }
        if (t == 0) dem[bb * 512 + co] = rsqrtf(S2 * red[0] + 1e-8f);
        __syncthreads();
    }
}

// ---------------------------------------------------------------------------
// Kernel 4: implicit-GEMM conv. 128 co x 128 spatial (2 rows x 64 w), 4 waves.
// Staging via global_load_lds width-16 (async DMA, no VGPR round-trip).
// LDS rows are 64 B (32 ci) with chunk-XOR swizzle: slot s of entry e holds
// global chunk s^(e&3); frag readers use q^(e&3) -> b128 reads conflict-free.
// ---------------------------------------------------------------------------
__global__ __launch_bounds__(256, 3) void k_conv(
    const __hip_bfloat16* __restrict__ xs,   // [8][66][66][512] padded
    const __hip_bfloat16* __restrict__ wb,   // [9][512][512] tap-major
    const float* __restrict__ demod,
    const float* __restrict__ noise,
    const float* __restrict__ bias,
    const float* __restrict__ nstr,
    float* __restrict__ out) {
    __shared__ __align__(16) char Xl[264 * 64];   // 4 rows x 66 cols, 16896 B
    __shared__ __align__(16) char Wl[384 * 64];   // 3 taps x 128 co, 24576 B

    const int t = threadIdx.x;
    const int bi = blockIdx.x;
    const int co0 = (bi & 3) * 128;
    const int h0 = ((bi >> 2) & 31) * 2;
    const int b = bi >> 7;
    const int lane = t & 63;
    const int wv = t >> 6;
    const int wm = wv & 1, wn = wv >> 1;
    const int q = lane >> 4, ln = lane & 15;

    f32x4 acc[4][4];
#pragma unroll
    for (int i = 0; i < 4; ++i)
#pragma unroll
        for (int j = 0; j < 4; ++j) acc[i][j] = (f32x4){0.f, 0.f, 0.f, 0.f};

    // ---- precompute staging source pointers (chunk-XOR swizzled) ----
    const char* xsb = (const char*)xs + (size_t)b * 66 * 66 * 1024;
    const char* xsrc[4];
#pragma unroll
    for (int i = 0; i < 4; ++i) {
        int g = i * 256 + t;
        int e = g >> 2, s = g & 3;
        int r = e / 66, c = e - r * 66;
        int gc = s ^ (e & 3);
        xsrc[i] = xsb + (size_t)((h0 + r) * 66 + c) * 1024 + gc * 16;
    }
    const char* xsrct = xsb;  // tail: entries 256..263 (row 3, cols 58..65)
    {
        int e = 256 + (t >> 2), s = t & 3;
        int c = e - 198;
        int gc = s ^ (e & 3);
        xsrct = xsb + (size_t)((h0 + 3) * 66 + c) * 1024 + gc * 16;
    }
    const char* wsrc[6];
#pragma unroll
    for (int i = 0; i < 6; ++i) {
        int g = i * 256 + t;
        int e = g >> 2, s = g & 3;
        int rr = e >> 7, co = e & 127;
        int gc = s ^ (co & 3);
        wsrc[i] = (const char*)wb +
                  ((size_t)rr * 262144 + (size_t)(co0 + co) * 512) * 2 + gc * 16;
    }
    char* ldsXw = Xl + (wv << 10);   // wave-uniform dst base (+ i*4096)
    char* ldsWw = Wl + (wv << 10);

    for (int cb = 0; cb < 16; ++cb) {
        const int cboff = cb * 64;
        __syncthreads();  // previous iteration's frag reads done
        // ---- async stage X (4 rows x 66 cols x 32 ci) ----
#pragma unroll
        for (int i = 0; i < 4; ++i)
            gload_lds16(xsrc[i] + cboff, ldsXw + i * 4096);
        if (t < 32) gload_lds16(xsrct + cboff, Xl + 16384);
        // ---- async stage W taps 0..2 ----
#pragma unroll
        for (int i = 0; i < 6; ++i)
            gload_lds16(wsrc[i] + cboff, ldsWw + i * 4096);
        __syncthreads();  // vmcnt(0) drain + barrier

        for (int dh = 0; dh < 3; ++dh) {
            if (dh) {
                __syncthreads();  // waves done reading Wl for dh-1
#pragma unroll
                for (int i = 0; i < 6; ++i)
                    gload_lds16(wsrc[i] + dh * 1572864 + cboff, ldsWw + i * 4096);
                __syncthreads();
            }
            const int xrow = dh + wn;
#pragma unroll
            for (int dw = 0; dw < 3; ++dw) {
                s16x8 af[4], bfr[4];
                const char* abase =
                    Wl + (dw * 128 + wm * 64 + ln) * 64 + ((q ^ (ln & 3)) << 4);
#pragma unroll
                for (int mi = 0; mi < 4; ++mi)
                    af[mi] = *(const s16x8*)(abase + mi * 1024);
                const int ecol = xrow * 66 + dw + ln;
                const char* bbase = Xl + ecol * 64 + ((q ^ (ecol & 3)) << 4);
#pragma unroll
                for (int ni = 0; ni < 4; ++ni)
                    bfr[ni] = *(const s16x8*)(bbase + ni * 1024);
#pragma unroll
                for (int mi = 0; mi < 4; ++mi)
#pragma unroll
                    for (int ni = 0; ni < 4; ++ni)
                        acc[mi][ni] = __builtin_amdgcn_mfma_f32_16x16x32_bf16(
                            af[mi], bfr[ni], acc[mi][ni], 0, 0, 0);
            }
        }
    }

    // ---- epilogue: *demod + noise*strength + bias, leaky_relu(0.2)*sqrt(2) ----
    const float nsv = nstr[0];
    const int h = h0 + wn;
    const float LR = 1.4142135623730951f;
#pragma unroll
    for (int mi = 0; mi < 4; ++mi) {
        float dm[4], bs[4];
#pragma unroll
        for (int r = 0; r < 4; ++r) {
            int co = co0 + wm * 64 + mi * 16 + q * 4 + r;
            dm[r] = demod[b * 512 + co];
            bs[r] = bias[co];
        }
#pragma unroll
        for (int ni = 0; ni < 4; ++ni) {
            int w = ni * 16 + ln;
            float nz = nsv * noise[h * 64 + w];
#pragma unroll
            for (int r = 0; r < 4; ++r) {
                int co = co0 + wm * 64 + mi * 16 + q * 4 + r;
                float v = acc[mi][ni][r] * dm[r] + nz + bs[r];
                v = (v >= 0.f ? v : 0.2f * v) * LR;
                out[(((size_t)b * 512 + co) * 64 + h) * 64 + w] = v;
            }
        }
    }
}

// ---------------------------------------------------------------------------
extern "C" void kernel_launch(void* const* d_in, const int* in_sizes, int n_in,
                              void* d_out, int out_size, void* d_ws, size_t ws_size,
                              hipStream_t stream) {
    const float* x      = (const float*)d_in[0];
    const float* style  = (const float*)d_in[1];
    const float* noise  = (const float*)d_in[2];
    const float* weight = (const float*)d_in[3];
    const float* bias   = (const float*)d_in[4];
    const float* nstr   = (const float*)d_in[5];
    float* out = (float*)d_out;

    char* ws = (char*)d_ws;
    __hip_bfloat16* xs = (__hip_bfloat16*)ws;              // 35,684,352 B padded
    __hip_bfloat16* wb = (__hip_bfloat16*)(ws + 35684352); //  4,718,592 B
    float* demod = (float*)(ws + 35684352 + 4718592);      //     16,384 B

    k_border<<<520, 256, 0, stream>>>(xs);
    k_xprep<<<dim3(4, 64, 8), 256, 0, stream>>>(x, style, xs);
    k_wprep<<<1024, 256, 0, stream>>>(weight, wb);
    k_demod<<<512, 256, 0, stream>>>(weight, style, demod);
    k_conv<<<1024, 256, 0, stream>>>(xs, wb, demod, noise, bias, nstr, out);
}

// Round 4
// 270.041 us; speedup vs baseline: 1.9421x; 1.0700x over previous
//
#include <hip/hip_runtime.h>
#include <hip/hip_bf16.h>

typedef __attribute__((ext_vector_type(8))) short s16x8;
typedef __attribute__((ext_vector_type(4))) float f32x4;

#define MOD_SCALE 0.014731391274719739f  // 1/sqrt(512*9)

__device__ __forceinline__ void gload_lds16(const void* g, void* l) {
    __builtin_amdgcn_global_load_lds(
        (const __attribute__((address_space(1))) unsigned int*)g,
        (__attribute__((address_space(3))) unsigned int*)l, 16, 0, 0);
}

// ---------------------------------------------------------------------------
// Fused prep kernel: blockIdx ranges
//   [0,520)      border zero of xs[8][66][66][512]
//   [520,2568)   xprep: x -> xs (padded, channels-last, *style*SCALE, bf16)
//   [2568,3592)  wprep: weight -> wb[tap][co][ci] bf16
//   [3592,4104)  demod
// ---------------------------------------------------------------------------
__global__ __launch_bounds__(256) void k_prep(const float* __restrict__ x,
                                              const float* __restrict__ style,
                                              const float* __restrict__ weight,
                                              __hip_bfloat16* __restrict__ xs,
                                              __hip_bfloat16* __restrict__ wb,
                                              float* __restrict__ dem) {
    __shared__ __align__(16) char sm[16896];
    const int t = threadIdx.x;
    const int bid = blockIdx.x;

    if (bid < 520) {
        // ---- border zero ----
        const int idx = bid * 256 + t;   // 0..133119
        const int b = idx / 16640;
        const int r2 = idx - b * 16640;
        const int pair = r2 >> 6;
        const int ciq = r2 & 63;
        int pr, pc;
        if (pair < 66)       { pr = 0;          pc = pair; }
        else if (pair < 132) { pr = 65;         pc = pair - 66; }
        else if (pair < 196) { pr = pair - 131; pc = 0; }
        else                 { pr = pair - 195; pc = 65; }
        uint4* d = (uint4*)(xs + (((size_t)b * 66 + pr) * 66 + pc) * 512) + ciq;
        *d = make_uint4(0u, 0u, 0u, 0u);
    } else if (bid < 2568) {
        // ---- xprep ----
        const int r = bid - 520;
        const int cig = r & 3, h = (r >> 2) & 63, b = r >> 8;
        const int ci0 = cig * 128;
        __hip_bfloat16 (*tile)[130] = (__hip_bfloat16(*)[130])sm;
        const int wl = t & 63, cl4 = t >> 6;
        for (int rr = 0; rr < 32; ++rr) {
            int c = rr * 4 + cl4;
            float v = x[(((size_t)b * 512 + ci0 + c) * 64 + h) * 64 + wl];
            float s = style[b * 512 + ci0 + c];
            tile[wl][c] = __float2bfloat16(v * s * MOD_SCALE);
        }
        __syncthreads();
        const int w4 = t >> 6;
        const int cp = (t & 63) * 2;
        for (int rr = 0; rr < 16; ++rr) {
            int w = rr * 4 + w4;
            unsigned v = *(const unsigned*)(&tile[w][cp]);
            *(unsigned*)(&xs[(((size_t)b * 66 + h + 1) * 66 + (w + 1)) * 512 +
                             ci0 + cp]) = v;
        }
    } else if (bid < 3592) {
        // ---- wprep ----
        const int r = bid - 2568;
        float* lds = (float*)sm;
        const int p0 = r * 256;
        const float* src = weight + (size_t)p0 * 9;
#pragma unroll
        for (int k = 0; k < 9; ++k) lds[k * 256 + t] = src[k * 256 + t];
        __syncthreads();
#pragma unroll
        for (int tap = 0; tap < 9; ++tap)
            wb[(size_t)tap * 262144 + p0 + t] = __float2bfloat16(lds[t * 9 + tap]);
    } else {
        // ---- demod: dem[b][co] = rsqrt(S2*sum_flat w^2 * style2[b][idx/9]+eps)
        const int co = bid - 3592;
        float* s2 = (float*)sm;                  // 4096 floats
        for (int i = t; i < 4096; i += 256) { float v = style[i]; s2[i] = v * v; }
        __syncthreads();
        const float4* wp = (const float4*)(weight + (size_t)co * 4608);
        float acc[8] = {0.f, 0.f, 0.f, 0.f, 0.f, 0.f, 0.f, 0.f};
        for (int j = t; j < 1152; j += 256) {
            float4 v = wp[j];
            float w2[4] = {v.x * v.x, v.y * v.y, v.z * v.z, v.w * v.w};
            int base = j * 4;
#pragma unroll
            for (int e = 0; e < 4; ++e) {
                int ci = (base + e) / 9;
                float ww = w2[e];
#pragma unroll
                for (int bb = 0; bb < 8; ++bb) acc[bb] += ww * s2[bb * 512 + ci];
            }
        }
#pragma unroll
        for (int bb = 0; bb < 8; ++bb)
            for (int off = 32; off > 0; off >>= 1)
                acc[bb] += __shfl_down(acc[bb], off);
        float* red = (float*)(sm + 16384);
        const int wv = t >> 6, lane = t & 63;
        if (lane == 0) {
#pragma unroll
            for (int bb = 0; bb < 8; ++bb) red[wv * 8 + bb] = acc[bb];
        }
        __syncthreads();
        if (t < 8) {
            float s = red[t] + red[8 + t] + red[16 + t] + red[24 + t];
            const float S2 = MOD_SCALE * MOD_SCALE;
            dem[t * 512 + co] = rsqrtf(S2 * s + 1e-8f);
        }
    }
}

// ---------------------------------------------------------------------------
// Conv: implicit GEMM, 128co x 128sp (2 rows x 64 w), 4 waves 2x2.
// Per-tap W staging (8 KB) double-buffered: prefetch W[g+1] issued right after
// the barrier, drained by the NEXT barrier after ~1 compute gap -> latency
// hidden. X staged once per ci-block (single buffer; exposed drain is L2-hit
// thanks to XCD-friendly mapping). LDS 33280 B -> 4 blocks/CU; grid 1024 =
// exactly one full-residency round (no tail).
// bi mapping: spat = bi&255 (b = spat>>5, h0 = (spat&31)*2), co0 = (bi>>8)*128
// -> the 4 co-blocks sharing an X tile have equal bi%8 (same XCD L2).
// ---------------------------------------------------------------------------
__global__ __launch_bounds__(256, 4) void k_conv(
    const __hip_bfloat16* __restrict__ xs,   // [8][66][66][512] padded
    const __hip_bfloat16* __restrict__ wb,   // [9][512][512] tap-major
    const float* __restrict__ demod,
    const float* __restrict__ noise,
    const float* __restrict__ bias,
    const float* __restrict__ nstr,
    float* __restrict__ out) {
    __shared__ __align__(16) char Xl[16896];     // 264 entries x 64 B
    __shared__ __align__(16) char Wl[2][8192];   // 128 co x 64 B, dbuf

    const int t = threadIdx.x;
    const int bi = blockIdx.x;
    const int spat = bi & 255;
    const int b = spat >> 5;
    const int h0 = (spat & 31) << 1;
    const int co0 = (bi >> 8) << 7;
    const int lane = t & 63;
    const int wv = t >> 6;
    const int wm = wv & 1, wn = wv >> 1;
    const int q = lane >> 4, ln = lane & 15;

    f32x4 acc[4][4];
#pragma unroll
    for (int i = 0; i < 4; ++i)
#pragma unroll
        for (int j = 0; j < 4; ++j) acc[i][j] = (f32x4){0.f, 0.f, 0.f, 0.f};

    // ---- staging source pointers (chunk-XOR swizzled) ----
    const char* xsb = (const char*)xs + (size_t)b * 66 * 66 * 1024;
    const char* xsrc[4];
#pragma unroll
    for (int i = 0; i < 4; ++i) {
        int g = i * 256 + t;
        int e = g >> 2, s = g & 3;
        int r = e / 66, c = e - r * 66;
        int gc = s ^ (e & 3);
        xsrc[i] = xsb + (size_t)((h0 + r) * 66 + c) * 1024 + gc * 16;
    }
    const char* xsrct;
    {
        int e = 256 + (t >> 2), s = t & 3;
        int c = e - 198;
        int gc = s ^ (e & 3);
        xsrct = xsb + (size_t)((h0 + 3) * 66 + c) * 1024 + gc * 16;
    }
    const char* wsrcb[2];
#pragma unroll
    for (int i = 0; i < 2; ++i) {
        int g = i * 256 + t;
        int e = g >> 2, s = g & 3;       // e = co 0..127
        int gc = s ^ (e & 3);
        wsrcb[i] = (const char*)wb + (size_t)(co0 + e) * 1024 + gc * 16;
    }
    char* ldsXw = Xl + (wv << 10);

    // ---- prologue: X[0] + W[g=0] -> buf0 ----
#pragma unroll
    for (int i = 0; i < 4; ++i) gload_lds16(xsrc[i], ldsXw + i * 4096);
    if (t < 32) gload_lds16(xsrct, Xl + 16384);
#pragma unroll
    for (int i = 0; i < 2; ++i)
        gload_lds16(wsrcb[i], Wl[0] + (wv << 10) + i * 4096);
    __syncthreads();

    int g = 0;
    for (int cb = 0; cb < 16; ++cb) {
        const int cboff = cb * 64;
#pragma unroll
        for (int tap = 0; tap < 9; ++tap, ++g) {
            // ---- prefetch next W tap (drained at this gap's closing barrier)
            if (tap < 8) {
#pragma unroll
                for (int i = 0; i < 2; ++i)
                    gload_lds16(wsrcb[i] + (tap + 1) * 524288 + cboff,
                                Wl[(g + 1) & 1] + (wv << 10) + i * 4096);
            } else if (cb < 15) {
#pragma unroll
                for (int i = 0; i < 2; ++i)
                    gload_lds16(wsrcb[i] + cboff + 64,
                                Wl[(g + 1) & 1] + (wv << 10) + i * 4096);
            }
            // ---- compute tap ----
            const int dh = tap / 3, dw = tap % 3;
            const char* Wb = Wl[g & 1];
            s16x8 af[4], bfr[4];
            const char* abase = Wb + (wm * 64 + ln) * 64 + ((q ^ (ln & 3)) << 4);
#pragma unroll
            for (int mi = 0; mi < 4; ++mi)
                af[mi] = *(const s16x8*)(abase + mi * 1024);
            const int ecol = (dh + wn) * 66 + dw + ln;
            const char* bbase = Xl + ecol * 64 + ((q ^ (ecol & 3)) << 4);
#pragma unroll
            for (int ni = 0; ni < 4; ++ni)
                bfr[ni] = *(const s16x8*)(bbase + ni * 1024);
#pragma unroll
            for (int mi = 0; mi < 4; ++mi)
#pragma unroll
                for (int ni = 0; ni < 4; ++ni)
                    acc[mi][ni] = __builtin_amdgcn_mfma_f32_16x16x32_bf16(
                        af[mi], bfr[ni], acc[mi][ni], 0, 0, 0);
            __syncthreads();
        }
        // ---- stage X[cb+1] (single buffer; all taps of cb done reading) ----
        if (cb < 15) {
#pragma unroll
            for (int i = 0; i < 4; ++i)
                gload_lds16(xsrc[i] + cboff + 64, ldsXw + i * 4096);
            if (t < 32) gload_lds16(xsrct + cboff + 64, Xl + 16384);
            __syncthreads();
        }
    }

    // ---- epilogue ----
    const float nsv = nstr[0];
    const int h = h0 + wn;
    const float LR = 1.4142135623730951f;
#pragma unroll
    for (int mi = 0; mi < 4; ++mi) {
        float dm[4], bs[4];
#pragma unroll
        for (int r = 0; r < 4; ++r) {
            int co = co0 + wm * 64 + mi * 16 + q * 4 + r;
            dm[r] = demod[b * 512 + co];
            bs[r] = bias[co];
        }
#pragma unroll
        for (int ni = 0; ni < 4; ++ni) {
            int w = ni * 16 + ln;
            float nz = nsv * noise[h * 64 + w];
#pragma unroll
            for (int r = 0; r < 4; ++r) {
                int co = co0 + wm * 64 + mi * 16 + q * 4 + r;
                float v = acc[mi][ni][r] * dm[r] + nz + bs[r];
                v = (v >= 0.f ? v : 0.2f * v) * LR;
                out[(((size_t)b * 512 + co) * 64 + h) * 64 + w] = v;
            }
        }
    }
}

// ---------------------------------------------------------------------------
extern "C" void kernel_launch(void* const* d_in, const int* in_sizes, int n_in,
                              void* d_out, int out_size, void* d_ws, size_t ws_size,
                              hipStream_t stream) {
    const float* x      = (const float*)d_in[0];
    const float* style  = (const float*)d_in[1];
    const float* noise  = (const float*)d_in[2];
    const float* weight = (const float*)d_in[3];
    const float* bias   = (const float*)d_in[4];
    const float* nstr   = (const float*)d_in[5];
    float* out = (float*)d_out;

    char* ws = (char*)d_ws;
    __hip_bfloat16* xs = (__hip_bfloat16*)ws;              // 35,684,352 B padded
    __hip_bfloat16* wb = (__hip_bfloat16*)(ws + 35684352); //  4,718,592 B
    float* demod = (float*)(ws + 35684352 + 4718592);      //     16,384 B

    k_prep<<<4104, 256, 0, stream>>>(x, style, weight, xs, wb, demod);
    k_conv<<<1024, 256, 0, stream>>>(xs, wb, demod, noise, bias, nstr, out);
}

// Round 6
// 254.754 us; speedup vs baseline: 2.0586x; 1.0600x over previous
//
#include <hip/hip_runtime.h>
#include <hip/hip_bf16.h>

typedef __attribute__((ext_vector_type(8))) short s16x8;
typedef __attribute__((ext_vector_type(16))) float f32x16;

#define MOD_SCALE 0.014731391274719739f  // 1/sqrt(512*9)

__device__ __forceinline__ void gload_lds16(const void* g, void* l) {
    __builtin_amdgcn_global_load_lds(
        (const __attribute__((address_space(1))) unsigned int*)g,
        (__attribute__((address_space(3))) unsigned int*)l, 16, 0, 0);
}

// Drain all counters then barrier. R5 post-mortem: the X-dbuf prefetch
// co-issued in the tap-8 gap raced under graph-replay load; R6 returns to
// R4's proven shape and adds an explicit full drain before every barrier.
__device__ __forceinline__ void sync_drain() {
    __builtin_amdgcn_s_waitcnt(0);
    __syncthreads();
}

// ---------------------------------------------------------------------------
// Fused prep kernel (unchanged, proven): blockIdx ranges
//   [0,520) border zero | [520,2568) xprep | [2568,3592) wprep | [3592,4104) demod
// ---------------------------------------------------------------------------
__global__ __launch_bounds__(256) void k_prep(const float* __restrict__ x,
                                              const float* __restrict__ style,
                                              const float* __restrict__ weight,
                                              __hip_bfloat16* __restrict__ xs,
                                              __hip_bfloat16* __restrict__ wb,
                                              float* __restrict__ dem) {
    __shared__ __align__(16) char sm[16896];
    const int t = threadIdx.x;
    const int bid = blockIdx.x;

    if (bid < 520) {
        const int idx = bid * 256 + t;
        const int b = idx / 16640;
        const int r2 = idx - b * 16640;
        const int pair = r2 >> 6;
        const int ciq = r2 & 63;
        int pr, pc;
        if (pair < 66)       { pr = 0;          pc = pair; }
        else if (pair < 132) { pr = 65;         pc = pair - 66; }
        else if (pair < 196) { pr = pair - 131; pc = 0; }
        else                 { pr = pair - 195; pc = 65; }
        uint4* d = (uint4*)(xs + (((size_t)b * 66 + pr) * 66 + pc) * 512) + ciq;
        *d = make_uint4(0u, 0u, 0u, 0u);
    } else if (bid < 2568) {
        const int r = bid - 520;
        const int cig = r & 3, h = (r >> 2) & 63, b = r >> 8;
        const int ci0 = cig * 128;
        __hip_bfloat16 (*tile)[130] = (__hip_bfloat16(*)[130])sm;
        const int wl = t & 63, cl4 = t >> 6;
        for (int rr = 0; rr < 32; ++rr) {
            int c = rr * 4 + cl4;
            float v = x[(((size_t)b * 512 + ci0 + c) * 64 + h) * 64 + wl];
            float s = style[b * 512 + ci0 + c];
            tile[wl][c] = __float2bfloat16(v * s * MOD_SCALE);
        }
        __syncthreads();
        const int w4 = t >> 6;
        const int cp = (t & 63) * 2;
        for (int rr = 0; rr < 16; ++rr) {
            int w = rr * 4 + w4;
            unsigned v = *(const unsigned*)(&tile[w][cp]);
            *(unsigned*)(&xs[(((size_t)b * 66 + h + 1) * 66 + (w + 1)) * 512 +
                             ci0 + cp]) = v;
        }
    } else if (bid < 3592) {
        const int r = bid - 2568;
        float* lds = (float*)sm;
        const int p0 = r * 256;
        const float* src = weight + (size_t)p0 * 9;
#pragma unroll
        for (int k = 0; k < 9; ++k) lds[k * 256 + t] = src[k * 256 + t];
        __syncthreads();
#pragma unroll
        for (int tap = 0; tap < 9; ++tap)
            wb[(size_t)tap * 262144 + p0 + t] = __float2bfloat16(lds[t * 9 + tap]);
    } else {
        const int co = bid - 3592;
        float* s2 = (float*)sm;
        for (int i = t; i < 4096; i += 256) { float v = style[i]; s2[i] = v * v; }
        __syncthreads();
        const float4* wp = (const float4*)(weight + (size_t)co * 4608);
        float acc[8] = {0.f, 0.f, 0.f, 0.f, 0.f, 0.f, 0.f, 0.f};
        for (int j = t; j < 1152; j += 256) {
            float4 v = wp[j];
            float w2[4] = {v.x * v.x, v.y * v.y, v.z * v.z, v.w * v.w};
            int base = j * 4;
#pragma unroll
            for (int e = 0; e < 4; ++e) {
                int ci = (base + e) / 9;
                float ww = w2[e];
#pragma unroll
                for (int bb = 0; bb < 8; ++bb) acc[bb] += ww * s2[bb * 512 + ci];
            }
        }
#pragma unroll
        for (int bb = 0; bb < 8; ++bb)
            for (int off = 32; off > 0; off >>= 1)
                acc[bb] += __shfl_down(acc[bb], off);
        float* red = (float*)(sm + 16384);
        const int wv = t >> 6, lane = t & 63;
        if (lane == 0) {
#pragma unroll
            for (int bb = 0; bb < 8; ++bb) red[wv * 8 + bb] = acc[bb];
        }
        __syncthreads();
        if (t < 8) {
            float s = red[t] + red[8 + t] + red[16 + t] + red[24 + t];
            const float S2 = MOD_SCALE * MOD_SCALE;
            dem[t * 512 + co] = rsqrtf(S2 * s + 1e-8f);
        }
    }
}

// ---------------------------------------------------------------------------
// Conv: implicit GEMM, 32x32x16 MFMA. Block 128co x 256sp (4 rows x 64 w),
// 4 waves (wm = co half, wn = row pair), wave tile 64co x 128sp (2x4 frags),
// 43.7 FLOP per LDS byte. Sync skeleton = R4's proven shape:
//   - W per-tap double-buffer, prefetch issued at tap top, drained at the
//     end-of-tap barrier (latency hidden by tap compute).
//   - X SINGLE buffer (6 rows x 66 x 64B), staged at each cb boundary
//     between a dedicated barrier pair.
// Rotation swizzle: LDS slot s of entry e holds global chunk (s-(e>>2))&3;
// readers use slot (c+(e>>2))&3 -> b128 reads spread 8 dwords/bank.
// Grid 512 = exactly 2 blocks/CU (LDS 41728 B, VGPR ~190 -> 2 waves/SIMD).
// ---------------------------------------------------------------------------
__global__ __launch_bounds__(256, 2) void k_conv(
    const __hip_bfloat16* __restrict__ xs,   // [8][66][66][512] padded
    const __hip_bfloat16* __restrict__ wb,   // [9][512][512] tap-major
    const float* __restrict__ demod,
    const float* __restrict__ noise,
    const float* __restrict__ bias,
    const float* __restrict__ nstr,
    float* __restrict__ out) {
    __shared__ __align__(16) char Xl[25344];     // 396 entries x 64 B
    __shared__ __align__(16) char Wl[2][8192];   // 128 co x 64 B, dbuf

    const int t = threadIdx.x;
    const int bi = blockIdx.x;
    const int spat = bi & 127;            // same spat -> same bi%8 -> same XCD
    const int b = spat >> 4;
    const int h0 = (spat & 15) << 2;
    const int co0 = (bi >> 7) << 7;
    const int lane = t & 63;
    const int wv = t >> 6;
    const int wm = wv & 1, wn = wv >> 1;
    const int el = lane & 31;
    const int hk = lane >> 5;

    f32x16 acc[2][4];
#pragma unroll
    for (int i = 0; i < 2; ++i)
#pragma unroll
        for (int j = 0; j < 4; ++j)
#pragma unroll
            for (int k = 0; k < 16; ++k) acc[i][j][k] = 0.f;

    // ---- staging source pointers (rotation-swizzled) ----
    const char* xsb = (const char*)xs + (size_t)b * 66 * 66 * 1024;
    const char* xsrc[7];
#pragma unroll
    for (int i = 0; i < 6; ++i) {
        int g = i * 256 + t;
        int e = g >> 2, s = g & 3;
        int gc = (s - (e >> 2)) & 3;
        int row = e / 66, col = e - row * 66;
        xsrc[i] = xsb + (size_t)((h0 + row) * 66 + col) * 1024 + gc * 16;
    }
    {   // tail entries 384..395 (threads 0..47 only use this)
        int g = 1536 + t;
        int e = g >> 2, s = g & 3;
        int gc = (s - (e >> 2)) & 3;
        int row = e / 66, col = e - row * 66;
        xsrc[6] = xsb + (size_t)((h0 + row) * 66 + col) * 1024 + gc * 16;
    }
    const char* wsrc[2];
#pragma unroll
    for (int i = 0; i < 2; ++i) {
        int g = i * 256 + t;
        int e = g >> 2, s = g & 3;
        int gc = (s - (e >> 2)) & 3;
        wsrc[i] = (const char*)wb + (size_t)(co0 + e) * 1024 + gc * 16;
    }
    const int wvoff = wv << 10;

    // ---- prologue: X(cb=0), W(tap0,cb0) -> buf0 ----
#pragma unroll
    for (int i = 0; i < 6; ++i) gload_lds16(xsrc[i], Xl + i * 4096 + wvoff);
    if (t < 48) gload_lds16(xsrc[6], Xl + 24576);
#pragma unroll
    for (int i = 0; i < 2; ++i)
        gload_lds16(wsrc[i], Wl[0] + i * 4096 + wvoff);
    sync_drain();

    int g = 0;
    for (int cb = 0; cb < 16; ++cb) {
        const int cboff = cb * 64;
#pragma unroll
        for (int tap = 0; tap < 9; ++tap, ++g) {
            // ---- prefetch next W tap into the other buffer ----
            if (tap < 8) {
                char* Wn = Wl[(g + 1) & 1] + wvoff;
#pragma unroll
                for (int i = 0; i < 2; ++i)
                    gload_lds16(wsrc[i] + (size_t)(tap + 1) * 524288 + cboff,
                                Wn + i * 4096);
            } else if (cb < 15) {
                char* Wn = Wl[(g + 1) & 1] + wvoff;
#pragma unroll
                for (int i = 0; i < 2; ++i)
                    gload_lds16(wsrc[i] + cboff + 64, Wn + i * 4096);
            }
            // ---- compute tap ----
            const int dh = tap / 3, dw = tap % 3;
            const char* Wb = Wl[g & 1];
#pragma unroll
            for (int ks = 0; ks < 2; ++ks) {
                const int c = 2 * ks + hk;
                s16x8 af[2], bfr[4];
#pragma unroll
                for (int mi = 0; mi < 2; ++mi) {
                    int e = wm * 64 + mi * 32 + el;
                    af[mi] = *(const s16x8*)(Wb + e * 64 +
                                             (((c + (e >> 2)) & 3) << 4));
                }
#pragma unroll
                for (int ni = 0; ni < 4; ++ni) {
                    int e = (2 * wn + (ni >> 1) + dh) * 66 + dw +
                            (ni & 1) * 32 + el;
                    bfr[ni] = *(const s16x8*)(Xl + e * 64 +
                                              (((c + (e >> 2)) & 3) << 4));
                }
#pragma unroll
                for (int mi = 0; mi < 2; ++mi)
#pragma unroll
                    for (int ni = 0; ni < 4; ++ni)
                        acc[mi][ni] = __builtin_amdgcn_mfma_f32_32x32x16_bf16(
                            af[mi], bfr[ni], acc[mi][ni], 0, 0, 0);
            }
            sync_drain();
        }
        // ---- restage X (single buffer, between its own barrier pair) ----
        if (cb < 15) {
#pragma unroll
            for (int i = 0; i < 6; ++i)
                gload_lds16(xsrc[i] + cboff + 64, Xl + i * 4096 + wvoff);
            if (t < 48) gload_lds16(xsrc[6] + cboff + 64, Xl + 24576);
            sync_drain();
        }
    }

    // ---- epilogue: *demod + noise*strength + bias, leaky_relu(0.2)*sqrt(2) ----
    const float nsv = nstr[0];
    const float LR = 1.4142135623730951f;
#pragma unroll
    for (int mi = 0; mi < 2; ++mi) {
        float dm[16], bs[16];
#pragma unroll
        for (int rg = 0; rg < 16; ++rg) {
            int co = co0 + wm * 64 + mi * 32 + (rg & 3) + 8 * (rg >> 2) + 4 * hk;
            dm[rg] = demod[b * 512 + co];
            bs[rg] = bias[co];
        }
#pragma unroll
        for (int ni = 0; ni < 4; ++ni) {
            int h = h0 + 2 * wn + (ni >> 1);
            int w = (ni & 1) * 32 + el;
            float nz = nsv * noise[h * 64 + w];
#pragma unroll
            for (int rg = 0; rg < 16; ++rg) {
                int co = co0 + wm * 64 + mi * 32 + (rg & 3) + 8 * (rg >> 2) +
                         4 * hk;
                float v = acc[mi][ni][rg] * dm[rg] + nz + bs[rg];
                v = (v >= 0.f ? v : 0.2f * v) * LR;
                out[(((size_t)b * 512 + co) * 64 + h) * 64 + w] = v;
            }
        }
    }
}

// ---------------------------------------------------------------------------
extern "C" void kernel_launch(void* const* d_in, const int* in_sizes, int n_in,
                              void* d_out, int out_size, void* d_ws, size_t ws_size,
                              hipStream_t stream) {
    const float* x      = (const float*)d_in[0];
    const float* style  = (const float*)d_in[1];
    const float* noise  = (const float*)d_in[2];
    const float* weight = (const float*)d_in[3];
    const float* bias   = (const float*)d_in[4];
    const float* nstr   = (const float*)d_in[5];
    float* out = (float*)d_out;

    char* ws = (char*)d_ws;
    __hip_bfloat16* xs = (__hip_bfloat16*)ws;              // 35,684,352 B padded
    __hip_bfloat16* wb = (__hip_bfloat16*)(ws + 35684352); //  4,718,592 B
    float* demod = (float*)(ws + 35684352 + 4718592);      //     16,384 B

    k_prep<<<4104, 256, 0, stream>>>(x, style, weight, xs, wb, demod);
    k_conv<<<512, 256, 0, stream>>>(xs, wb, demod, noise, bias, nstr, out);
}